// Round 12
// baseline (76.032 us; speedup 1.0000x reference)
//
#include <hip/hip_runtime.h>
#include <math.h>

#define THREADS 256
#define GAMMA 0.99

typedef float vf4 __attribute__((ext_vector_type(4)));   // native vector for nontemporal store

__device__ __forceinline__ int padi16(int i) { return i + (i >> 4); }   // lane stride 17 floats

// ---------- block-wide exclusive scan of linear transforms x -> g*x + v (f64) ----------
template<int NW>
__device__ __forceinline__ void block_compose_excl(int tid, double g, double v,
                                                   double& eg, double& ev,
                                                   double* lg, double* lv) {
    const int lane = tid & 63, wave = tid >> 6;
    double ig = g, iv = v;
#pragma unroll
    for (int k = 1; k < 64; k <<= 1) {
        double og = __shfl_up(ig, k);
        double ov = __shfl_up(iv, k);
        if (lane >= k) { iv = fma(ig, ov, iv); ig *= og; }
    }
    double weg = __shfl_up(ig, 1);
    double wev = __shfl_up(iv, 1);
    if (lane == 0) { weg = 1.0; wev = 0.0; }
    if (lane == 63) { lg[wave] = ig; lv[wave] = iv; }
    __syncthreads();
    double bg = 1.0, bv = 0.0;
    for (int w = 0; w < wave; ++w) { bv = fma(lg[w], bv, lv[w]); bg *= lg[w]; }
    eg = weg * bg;
    ev = fma(weg, bv, wev);
}

// ---------- block-wide exclusive additive scan of a pair (f64) ----------
template<int NW>
__device__ __forceinline__ void block_add_excl2(int tid, double a, double b,
                                                double& ea, double& eb,
                                                double* la, double* lb) {
    const int lane = tid & 63, wave = tid >> 6;
    double ia = a, ib = b;
#pragma unroll
    for (int k = 1; k < 64; k <<= 1) {
        double oa = __shfl_up(ia, k);
        double ob = __shfl_up(ib, k);
        if (lane >= k) { ia += oa; ib += ob; }
    }
    double wea = __shfl_up(ia, 1);
    double web = __shfl_up(ib, 1);
    if (lane == 0) { wea = 0.0; web = 0.0; }
    if (lane == 63) { la[wave] = ia; lb[wave] = ib; }
    __syncthreads();
    double ba = 0.0, bb = 0.0;
    for (int w = 0; w < wave; ++w) { ba += la[w]; bb += lb[w]; }
    ea = wea + ba;
    eb = web + bb;
}

// ================= wave-granular: chunk = 1024 elems per wave =================
// aggf[w] = float4{A,Ps,Pq,P2}   per 1024-elem wave chunk (f32-native)
// bagg[b*4+{A,Ps,Pq,P2}] (f64)   per 4096-elem block chunk
// wcar[w*3+{Rin,S1C,S2C}] (f64)  per wave chunk (exclusive), written by phase2

// ---------- W-Phase 1: per-wave aggregates + block-level fold ----------
__global__ __launch_bounds__(THREADS) void w_phase1(const float* __restrict__ in,
                                                    vf4* __restrict__ aggf,
                                                    double* __restrict__ bagg, int nw) {
    __shared__ double sA[4], sPs[4], sPq[4], sP2[4];
    const int tid = threadIdx.x, lane = tid & 63, w = tid >> 6;
    const int wid = blockIdx.x * 4 + w;

    const float* src = in + (size_t)wid * 1024 + (size_t)lane * 16;
    float rv[16];
#pragma unroll
    for (int q = 0; q < 4; ++q) {
        const float4 t = ((const float4*)src)[q];
        rv[4 * q] = t.x; rv[4 * q + 1] = t.y; rv[4 * q + 2] = t.z; rv[4 * q + 3] = t.w;
    }
    const float gf = (float)GAMMA;
    float p = 0.f, psum = 0.f, pq = 0.f, p2 = 0.f, gp = 1.f;
#pragma unroll
    for (int j = 0; j < 16; ++j) {
        p = fmaf(gf, p, rv[j]);
        gp *= gf;
        psum += p;
        pq = fmaf(gp, p, pq);
        p2 = fmaf(p, p, p2);
    }
    const double g = GAMMA;
    double gPT = g;
#pragma unroll
    for (int e = 0; e < 4; ++e) gPT *= gPT;     // g^16

    float ig = (float)gPT, iv = p;
#pragma unroll
    for (int k = 1; k < 64; k <<= 1) {
        float og = __shfl_up(ig, k);
        float ov = __shfl_up(iv, k);
        if (lane >= k) { iv = fmaf(ig, ov, iv); ig *= og; }
    }
    float rho = __shfl_up(iv, 1), gexc = __shfl_up(ig, 1);
    if (lane == 0) { rho = 0.f; gexc = 1.f; }
    const float A = __shfl(iv, 63);             // wave-chunk end value (zero-init)

    const float G1f = (float)(g * (1.0 - gPT) / (1.0 - g));
    const float G2f = (float)(g * g * (1.0 - gPT * gPT) / (1.0 - g * g));
    float c1 = fmaf(rho, G1f, psum);
    float c2 = gexc * fmaf(rho, G2f, pq);
    float c3 = fmaf(rho * rho, G2f, fmaf(2.f * rho, pq, p2));
#pragma unroll
    for (int k = 32; k > 0; k >>= 1) {
        c1 += __shfl_down(c1, k);
        c2 += __shfl_down(c2, k);
        c3 += __shfl_down(c3, k);
    }
    if (lane == 0) {
        vf4 a; a.x = A; a.y = c1; a.z = c2; a.w = c3;
        aggf[wid] = a;
        sA[w] = (double)A; sPs[w] = (double)c1; sPq[w] = (double)c2; sP2[w] = (double)c3;
    }
    __syncthreads();
    if (tid == 0) {
        double gC = g;
#pragma unroll
        for (int e = 0; e < 10; ++e) gC *= gC;      // g^1024
        const double G1C = g * (1.0 - gC) / (1.0 - g);
        const double G2C = g * g * (1.0 - gC * gC) / (1.0 - g * g);
        double Rin = 0.0, Ps = 0.0, Pq = 0.0, P2 = 0.0, gex = 1.0;
#pragma unroll
        for (int i = 0; i < 4; ++i) {
            Ps += fma(Rin, G1C, sPs[i]);
            Pq += gex * fma(Rin, G2C, sPq[i]);
            P2 += fma(Rin * Rin, G2C, fma(2.0 * Rin, sPq[i], sP2[i]));
            Rin = fma(gC, Rin, sA[i]);
            gex *= gC;
        }
        bagg[4 * (size_t)blockIdx.x + 0] = Rin;     // block end value
        bagg[4 * (size_t)blockIdx.x + 1] = Ps;
        bagg[4 * (size_t)blockIdx.x + 2] = Pq;
        bagg[4 * (size_t)blockIdx.x + 3] = P2;
    }
}

// ---------- Phase 2: scan block carries, then expand to per-wave carries ----------
template<int CPT, int LOG2CHUNK>
__global__ __launch_bounds__(1024) void rs_phase2x(const double* __restrict__ bagg,
                                                   const vf4* __restrict__ aggf,
                                                   double* __restrict__ wcar, int nchunk) {
    __shared__ double lg[16], lv[16], la[16], lb[16];
    const int t = threadIdx.x;
    const double g = GAMMA;
    double gC = g;
#pragma unroll
    for (int e = 0; e < LOG2CHUNK; ++e) gC *= gC;   // g^4096 (block chunk)
    double gW = g;
#pragma unroll
    for (int e = 0; e < 10; ++e) gW *= gW;          // g^1024 (wave chunk)

    double A[CPT], Ps[CPT], Pq[CPT], P2[CPT];
    const int c0 = t * CPT;
#pragma unroll
    for (int i = 0; i < CPT; ++i) {
        const int c = c0 + i;
        const bool ok = c < nchunk;
        A[i]  = ok ? bagg[4 * (size_t)c + 0] : 0.0;
        Ps[i] = ok ? bagg[4 * (size_t)c + 1] : 0.0;
        Pq[i] = ok ? bagg[4 * (size_t)c + 2] : 0.0;
        P2[i] = ok ? bagg[4 * (size_t)c + 3] : 0.0;
    }
    double mg = 1.0, mv = 0.0;
#pragma unroll
    for (int i = 0; i < CPT; ++i) { mv = fma(gC, mv, A[i]); mg *= gC; }

    double eg, ev;
    block_compose_excl<16>(t, mg, mv, eg, ev, lg, lv);

    const double G1C = g * (1.0 - gC) / (1.0 - g);
    const double G2C = g * g * (1.0 - gC * gC) / (1.0 - g * g);
    const double G1W = g * (1.0 - gW) / (1.0 - g);
    const double G2W = g * g * (1.0 - gW * gW) / (1.0 - g * g);

    double Rin[CPT + 1];
    Rin[0] = ev;
    double s1[CPT], s2[CPT];
#pragma unroll
    for (int i = 0; i < CPT; ++i) {
        s1[i] = fma(Rin[i], G1C, Ps[i]);
        s2[i] = fma(Rin[i] * Rin[i], G2C, fma(2.0 * Rin[i], Pq[i], P2[i]));
        Rin[i + 1] = fma(gC, Rin[i], A[i]);
    }
    double ts1 = 0.0, ts2 = 0.0;
#pragma unroll
    for (int i = 0; i < CPT; ++i) { ts1 += s1[i]; ts2 += s2[i]; }
    double ea, eb;
    block_add_excl2<16>(t, ts1, ts2, ea, eb, la, lb);

    // expand each block carry to its 4 wave carries (parallel across 1024 threads)
#pragma unroll
    for (int i = 0; i < CPT; ++i) {
        const int c = c0 + i;
        if (c < nchunk) {
            double wR = Rin[i], wS1 = ea, wS2 = eb;
#pragma unroll
            for (int j = 0; j < 4; ++j) {
                const int wd = 4 * c + j;
                wcar[3 * (size_t)wd + 0] = wR;
                wcar[3 * (size_t)wd + 1] = wS1;
                wcar[3 * (size_t)wd + 2] = wS2;
                const vf4 a = aggf[wd];
                const double Aw = (double)a.x, Pw = (double)a.y;
                const double Qw = (double)a.z, Sw = (double)a.w;
                wS1 += fma(wR, G1W, Pw);
                wS2 += fma(wR * wR, G2W, fma(2.0 * wR, Qw, Sw));
                wR = fma(gW, wR, Aw);
            }
        }
        ea += s1[i];
        eb += s2[i];
    }
}

// ---------- W-Phase 3: wave-independent rebase + emit; no block barriers ----------
__global__ __launch_bounds__(THREADS) void w_phase3(const float* __restrict__ in,
                                                    float* __restrict__ out,
                                                    const double* __restrict__ wcar, int nw) {
    __shared__ float sbuf[THREADS / 64][1024 + 64];   // private per-wave region, stride 17/lane
    const int tid = threadIdx.x, lane = tid & 63, w = tid >> 6;
    const int wid = blockIdx.x * 4 + w;

    // uniform per-wave carry: issue early, hides under input load
    const double RinC = wcar[3 * (size_t)wid + 0];
    const double S1C  = wcar[3 * (size_t)wid + 1];
    const double S2C  = wcar[3 * (size_t)wid + 2];

    const float* src = in + (size_t)wid * 1024 + (size_t)lane * 16;
    float rv[16];
#pragma unroll
    for (int q = 0; q < 4; ++q) {
        const float4 t = ((const float4*)src)[q];
        rv[4 * q] = t.x; rv[4 * q + 1] = t.y; rv[4 * q + 2] = t.z; rv[4 * q + 3] = t.w;
    }
    const float gf = (float)GAMMA;
    float p = 0.f, psum = 0.f, pq = 0.f, p2 = 0.f, gp = 1.f;
#pragma unroll
    for (int j = 0; j < 16; ++j) {
        p = fmaf(gf, p, rv[j]);
        gp *= gf;
        psum += p;
        pq = fmaf(gp, p, pq);
        p2 = fmaf(p, p, p2);
    }
    const double g = GAMMA;
    double gPT = g;
#pragma unroll
    for (int e = 0; e < 4; ++e) gPT *= gPT;     // g^16

    if (wid == 0) {
        // f64 wave path for the small-cnt region (cancellation-sensitive)
        double ig = gPT, iv = (double)p;
#pragma unroll
        for (int k = 1; k < 64; k <<= 1) {
            double og = __shfl_up(ig, k);
            double ov = __shfl_up(iv, k);
            if (lane >= k) { iv = fma(ig, ov, iv); ig *= og; }
        }
        double rho = __shfl_up(iv, 1), gexc = __shfl_up(ig, 1);
        if (lane == 0) { rho = 0.0; gexc = 1.0; }
        const double rin = fma(gexc, RinC, rho);
        const double G1 = g * (1.0 - gPT) / (1.0 - g);
        const double G2 = g * g * (1.0 - gPT * gPT) / (1.0 - g * g);
        double s1 = fma(rin, G1, (double)psum);
        double s2 = fma(rin * rin, G2, fma(2.0 * rin, (double)pq, (double)p2));
        double ia = s1, ib = s2;
#pragma unroll
        for (int k = 1; k < 64; k <<= 1) {
            double oa = __shfl_up(ia, k);
            double ob = __shfl_up(ib, k);
            if (lane >= k) { ia += oa; ib += ob; }
        }
        double ea = __shfl_up(ia, 1), eb = __shfl_up(ib, 1);
        if (lane == 0) { ea = 0.0; eb = 0.0; }
        double R = rin, S1 = S1C + ea, S2 = S2C + eb;
        const int a0 = lane * 17;
        const size_t gbase = (size_t)lane * 16;
        for (int j = 0; j < 16; ++j) {
            const float rf = rv[j];
            R = fma(g, R, (double)rf);
            S1 += R;
            S2 = fma(R, R, S2);
            float ov;
            if (gbase + j == 0) {
                ov = rf;                         // cnt < 2 -> std = 1
            } else {
                const double cnt = (double)(gbase + j + 1);
                const double inv = 1.0 / cnt;
                const double mean = S1 * inv;
                double var = fma(S2, inv, -(mean * mean));
                var = var > 0.0 ? var : 0.0;
                double sd = sqrt(var);
                sd = sd > 1e-8 ? sd : 1e-8;
                ov = (float)((double)rf / sd);
            }
            sbuf[w][a0 + j] = ov;
        }
    } else {
        // f32 wave path: cnt >= 1025, S2*cnt - S1^2 has no cancellation
        float ig = (float)gPT, iv = p;
#pragma unroll
        for (int k = 1; k < 64; k <<= 1) {
            float og = __shfl_up(ig, k);
            float ov = __shfl_up(iv, k);
            if (lane >= k) { iv = fmaf(ig, ov, iv); ig *= og; }
        }
        float rho = __shfl_up(iv, 1), gexc = __shfl_up(ig, 1);
        if (lane == 0) { rho = 0.f; gexc = 1.f; }
        const float rin = fmaf(gexc, (float)RinC, rho);
        const float G1f = (float)(g * (1.0 - gPT) / (1.0 - g));
        const float G2f = (float)(g * g * (1.0 - gPT * gPT) / (1.0 - g * g));
        float s1 = fmaf(rin, G1f, psum);
        float s2 = fmaf(rin * rin, G2f, fmaf(2.f * rin, pq, p2));
        float ia = s1, ib = s2;
#pragma unroll
        for (int k = 1; k < 64; k <<= 1) {
            float oa = __shfl_up(ia, k);
            float ob = __shfl_up(ib, k);
            if (lane >= k) { ia += oa; ib += ob; }
        }
        float ea = __shfl_up(ia, 1), eb = __shfl_up(ib, 1);
        if (lane == 0) { ea = 0.f; eb = 0.f; }
        const float S1bf = (float)S1C + ea;
        const float S2bf = (float)S2C + eb;

        float R = rin;
        float ls1 = 0.f, ls2 = 0.f;
        const float base_cnt = (float)((size_t)wid * 1024 + (size_t)lane * 16);
        const int a0 = lane * 17;
#pragma unroll
        for (int j = 0; j < 16; ++j) {
            const float rf = rv[j];
            R = fmaf(gf, R, rf);
            ls1 += R;
            ls2 = fmaf(R, R, ls2);
            const float cnt = base_cnt + (float)(j + 1);
            const float S1f = S1bf + ls1;
            const float S2f = S2bf + ls2;
            float t = fmaf(S2f, cnt, -(S1f * S1f));
            t = fmaxf(t, 1e-12f);
            sbuf[w][a0 + j] = rf * cnt * __builtin_amdgcn_rsqf(t);
        }
    }

    // wave-local sync only: this wave's ds_writes drain, then read own region.
    asm volatile("s_waitcnt lgkmcnt(0)" ::: "memory");

    float* dst = out + (size_t)wid * 1024;
#pragma unroll
    for (int k = 0; k < 4; ++k) {
        const int i = lane * 4 + k * 256;
        const int pp = padi16(i);
        vf4 v;
        v.x = sbuf[w][pp]; v.y = sbuf[w][pp + 1]; v.z = sbuf[w][pp + 2]; v.w = sbuf[w][pp + 3];
        __builtin_nontemporal_store(v, (vf4*)(dst + i));   // lane-contiguous full-line nt stores
    }
}

extern "C" void kernel_launch(void* const* d_in, const int* in_sizes, int n_in,
                              void* d_out, int out_size, void* d_ws, size_t ws_size,
                              hipStream_t stream) {
    (void)n_in; (void)out_size; (void)ws_size;
    const float* in = (const float*)d_in[0];
    float* out = (float*)d_out;
    double* ws = (double*)d_ws;
    const int n = in_sizes[0];

    const int nw = n >> 10;                     // 1024-elem wave chunks
    const int nc = nw >> 2;                     // 4096-elem block chunks
    // layout: bagg (4*nc f64) | wcar (3*nw f64) | aggf (nw float4)
    double* bagg = ws;
    double* wcar = ws + 4 * (size_t)nc;
    vf4* aggf = (vf4*)(wcar + 3 * (size_t)nw);

    w_phase1<<<nc, THREADS, 0, stream>>>(in, aggf, bagg, nw);
    rs_phase2x<4, 12><<<1, 1024, 0, stream>>>(bagg, aggf, wcar, nc);
    w_phase3<<<nc, THREADS, 0, stream>>>(in, out, wcar, nw);
}

// Round 13
// 53.710 us; speedup vs baseline: 1.4156x; 1.4156x over previous
//
#include <hip/hip_runtime.h>
#include <math.h>

#define THREADS 256
#define GAMMA 0.99

typedef float vf4 __attribute__((ext_vector_type(4)));   // native vector for nontemporal store

__device__ __forceinline__ int padi16(int i) { return i + (i >> 4); }   // lane stride 17 floats

// ---------- block-wide exclusive scan of linear transforms x -> g*x + v (f64) ----------
template<int NW>
__device__ __forceinline__ void block_compose_excl(int tid, double g, double v,
                                                   double& eg, double& ev,
                                                   double* lg, double* lv) {
    const int lane = tid & 63, wave = tid >> 6;
    double ig = g, iv = v;
#pragma unroll
    for (int k = 1; k < 64; k <<= 1) {
        double og = __shfl_up(ig, k);
        double ov = __shfl_up(iv, k);
        if (lane >= k) { iv = fma(ig, ov, iv); ig *= og; }
    }
    double weg = __shfl_up(ig, 1);
    double wev = __shfl_up(iv, 1);
    if (lane == 0) { weg = 1.0; wev = 0.0; }
    if (lane == 63) { lg[wave] = ig; lv[wave] = iv; }
    __syncthreads();
    double bg = 1.0, bv = 0.0;
    for (int w = 0; w < wave; ++w) { bv = fma(lg[w], bv, lv[w]); bg *= lg[w]; }
    eg = weg * bg;
    ev = fma(weg, bv, wev);
}

// ---------- block-wide exclusive additive scan of a pair (f64) ----------
template<int NW>
__device__ __forceinline__ void block_add_excl2(int tid, double a, double b,
                                                double& ea, double& eb,
                                                double* la, double* lb) {
    const int lane = tid & 63, wave = tid >> 6;
    double ia = a, ib = b;
#pragma unroll
    for (int k = 1; k < 64; k <<= 1) {
        double oa = __shfl_up(ia, k);
        double ob = __shfl_up(ib, k);
        if (lane >= k) { ia += oa; ib += ob; }
    }
    double wea = __shfl_up(ia, 1);
    double web = __shfl_up(ib, 1);
    if (lane == 0) { wea = 0.0; web = 0.0; }
    if (lane == 63) { la[wave] = ia; lb[wave] = ib; }
    __syncthreads();
    double ba = 0.0, bb = 0.0;
    for (int w = 0; w < wave; ++w) { ba += la[w]; bb += lb[w]; }
    ea = wea + ba;
    eb = web + bb;
}

// ================= wave-granular: chunk = 1024 elems per wave =================
// aggf[w] = float4{A,Ps,Pq,P2}   per 1024-elem wave chunk (f32-native)
// bagg[b*4+{A,Ps,Pq,P2}] (f64)   per 4096-elem block chunk
// bcar[b*3+{Rin,S1C,S2C}] (f64)  per block chunk (exclusive)
// wcar[w*3+{Rin,S1C,S2C}] (f64)  per wave chunk (exclusive)

// ---------- P1: per-wave aggregates + block-level fold ----------
__global__ __launch_bounds__(THREADS) void w_phase1(const float* __restrict__ in,
                                                    vf4* __restrict__ aggf,
                                                    double* __restrict__ bagg, int nw) {
    __shared__ double sA[4], sPs[4], sPq[4], sP2[4];
    const int tid = threadIdx.x, lane = tid & 63, w = tid >> 6;
    const int wid = blockIdx.x * 4 + w;

    const float* src = in + (size_t)wid * 1024 + (size_t)lane * 16;
    float rv[16];
#pragma unroll
    for (int q = 0; q < 4; ++q) {
        const float4 t = ((const float4*)src)[q];
        rv[4 * q] = t.x; rv[4 * q + 1] = t.y; rv[4 * q + 2] = t.z; rv[4 * q + 3] = t.w;
    }
    const float gf = (float)GAMMA;
    float p = 0.f, psum = 0.f, pq = 0.f, p2 = 0.f, gp = 1.f;
#pragma unroll
    for (int j = 0; j < 16; ++j) {
        p = fmaf(gf, p, rv[j]);
        gp *= gf;
        psum += p;
        pq = fmaf(gp, p, pq);
        p2 = fmaf(p, p, p2);
    }
    const double g = GAMMA;
    double gPT = g;
#pragma unroll
    for (int e = 0; e < 4; ++e) gPT *= gPT;     // g^16

    float ig = (float)gPT, iv = p;
#pragma unroll
    for (int k = 1; k < 64; k <<= 1) {
        float og = __shfl_up(ig, k);
        float ov = __shfl_up(iv, k);
        if (lane >= k) { iv = fmaf(ig, ov, iv); ig *= og; }
    }
    float rho = __shfl_up(iv, 1), gexc = __shfl_up(ig, 1);
    if (lane == 0) { rho = 0.f; gexc = 1.f; }
    const float A = __shfl(iv, 63);             // wave-chunk end value (zero-init)

    const float G1f = (float)(g * (1.0 - gPT) / (1.0 - g));
    const float G2f = (float)(g * g * (1.0 - gPT * gPT) / (1.0 - g * g));
    float c1 = fmaf(rho, G1f, psum);
    float c2 = gexc * fmaf(rho, G2f, pq);
    float c3 = fmaf(rho * rho, G2f, fmaf(2.f * rho, pq, p2));
#pragma unroll
    for (int k = 32; k > 0; k >>= 1) {
        c1 += __shfl_down(c1, k);
        c2 += __shfl_down(c2, k);
        c3 += __shfl_down(c3, k);
    }
    if (lane == 0) {
        vf4 a; a.x = A; a.y = c1; a.z = c2; a.w = c3;
        aggf[wid] = a;
        sA[w] = (double)A; sPs[w] = (double)c1; sPq[w] = (double)c2; sP2[w] = (double)c3;
    }
    __syncthreads();
    if (tid == 0) {
        double gC = g;
#pragma unroll
        for (int e = 0; e < 10; ++e) gC *= gC;      // g^1024
        const double G1C = g * (1.0 - gC) / (1.0 - g);
        const double G2C = g * g * (1.0 - gC * gC) / (1.0 - g * g);
        double Rin = 0.0, Ps = 0.0, Pq = 0.0, P2 = 0.0, gex = 1.0;
#pragma unroll
        for (int i = 0; i < 4; ++i) {
            Ps += fma(Rin, G1C, sPs[i]);
            Pq += gex * fma(Rin, G2C, sPq[i]);
            P2 += fma(Rin * Rin, G2C, fma(2.0 * Rin, sPq[i], sP2[i]));
            Rin = fma(gC, Rin, sA[i]);
            gex *= gC;
        }
        bagg[4 * (size_t)blockIdx.x + 0] = Rin;     // block end value
        bagg[4 * (size_t)blockIdx.x + 1] = Ps;
        bagg[4 * (size_t)blockIdx.x + 2] = Pq;
        bagg[4 * (size_t)blockIdx.x + 3] = P2;
    }
}

// ---------- P2: scan block carries (verified round-9 kernel) ----------
template<int CPT, int LOG2CHUNK>
__global__ __launch_bounds__(1024) void rs_phase2(const double* __restrict__ agg,
                                                  double* __restrict__ car, int nchunk) {
    __shared__ double lg[16], lv[16], la[16], lb[16];
    const int t = threadIdx.x;
    const double g = GAMMA;
    double gC = g;
#pragma unroll
    for (int e = 0; e < LOG2CHUNK; ++e) gC *= gC;   // g^CHUNKE

    double A[CPT], Ps[CPT], Pq[CPT], P2[CPT];
    const int c0 = t * CPT;
#pragma unroll
    for (int i = 0; i < CPT; ++i) {
        const int c = c0 + i;
        const bool ok = c < nchunk;
        A[i]  = ok ? agg[4 * (size_t)c + 0] : 0.0;
        Ps[i] = ok ? agg[4 * (size_t)c + 1] : 0.0;
        Pq[i] = ok ? agg[4 * (size_t)c + 2] : 0.0;
        P2[i] = ok ? agg[4 * (size_t)c + 3] : 0.0;
    }
    double mg = 1.0, mv = 0.0;
#pragma unroll
    for (int i = 0; i < CPT; ++i) { mv = fma(gC, mv, A[i]); mg *= gC; }

    double eg, ev;
    block_compose_excl<16>(t, mg, mv, eg, ev, lg, lv);

    const double G1C = g * (1.0 - gC) / (1.0 - g);
    const double G2C = g * g * (1.0 - gC * gC) / (1.0 - g * g);
    double Rin[CPT + 1];
    Rin[0] = ev;
    double s1[CPT], s2[CPT];
#pragma unroll
    for (int i = 0; i < CPT; ++i) {
        s1[i] = fma(Rin[i], G1C, Ps[i]);
        s2[i] = fma(Rin[i] * Rin[i], G2C, fma(2.0 * Rin[i], Pq[i], P2[i]));
        Rin[i + 1] = fma(gC, Rin[i], A[i]);
    }
    double ts1 = 0.0, ts2 = 0.0;
#pragma unroll
    for (int i = 0; i < CPT; ++i) { ts1 += s1[i]; ts2 += s2[i]; }
    double ea, eb;
    block_add_excl2<16>(t, ts1, ts2, ea, eb, la, lb);
#pragma unroll
    for (int i = 0; i < CPT; ++i) {
        const int c = c0 + i;
        if (c < nchunk) {
            car[3 * (size_t)c + 0] = Rin[i];
            car[3 * (size_t)c + 1] = ea;
            car[3 * (size_t)c + 2] = eb;
        }
        ea += s1[i];
        eb += s2[i];
    }
}

// ---------- P2b: parallel expansion block carry -> 4 wave carries ----------
__global__ __launch_bounds__(THREADS) void w_expand(const double* __restrict__ bcar,
                                                    const vf4* __restrict__ aggf,
                                                    double* __restrict__ wcar, int nc) {
    const int c = blockIdx.x * THREADS + threadIdx.x;
    if (c >= nc) return;
    const double g = GAMMA;
    double gW = g;
#pragma unroll
    for (int e = 0; e < 10; ++e) gW *= gW;          // g^1024
    const double G1W = g * (1.0 - gW) / (1.0 - g);
    const double G2W = g * g * (1.0 - gW * gW) / (1.0 - g * g);

    // independent loads issued up front
    const vf4 a0 = aggf[4 * (size_t)c + 0];
    const vf4 a1 = aggf[4 * (size_t)c + 1];
    const vf4 a2 = aggf[4 * (size_t)c + 2];
    const vf4 a3 = aggf[4 * (size_t)c + 3];
    double wR  = bcar[3 * (size_t)c + 0];
    double wS1 = bcar[3 * (size_t)c + 1];
    double wS2 = bcar[3 * (size_t)c + 2];

    const vf4 aj[4] = {a0, a1, a2, a3};
#pragma unroll
    for (int j = 0; j < 4; ++j) {
        const size_t wd = 4 * (size_t)c + j;
        wcar[3 * wd + 0] = wR;
        wcar[3 * wd + 1] = wS1;
        wcar[3 * wd + 2] = wS2;
        const double Aw = (double)aj[j].x, Pw = (double)aj[j].y;
        const double Qw = (double)aj[j].z, Sw = (double)aj[j].w;
        wS1 += fma(wR, G1W, Pw);
        wS2 += fma(wR * wR, G2W, fma(2.0 * wR, Qw, Sw));
        wR = fma(gW, wR, Aw);
    }
}

// ---------- P3: wave-independent rebase + emit; no block barriers ----------
__global__ __launch_bounds__(THREADS) void w_phase3(const float* __restrict__ in,
                                                    float* __restrict__ out,
                                                    const double* __restrict__ wcar, int nw) {
    __shared__ float sbuf[THREADS / 64][1024 + 64];   // private per-wave region, stride 17/lane
    const int tid = threadIdx.x, lane = tid & 63, w = tid >> 6;
    const int wid = blockIdx.x * 4 + w;

    // uniform per-wave carry: issue early, hides under input load
    const double RinC = wcar[3 * (size_t)wid + 0];
    const double S1C  = wcar[3 * (size_t)wid + 1];
    const double S2C  = wcar[3 * (size_t)wid + 2];

    const float* src = in + (size_t)wid * 1024 + (size_t)lane * 16;
    float rv[16];
#pragma unroll
    for (int q = 0; q < 4; ++q) {
        const float4 t = ((const float4*)src)[q];
        rv[4 * q] = t.x; rv[4 * q + 1] = t.y; rv[4 * q + 2] = t.z; rv[4 * q + 3] = t.w;
    }
    const float gf = (float)GAMMA;
    float p = 0.f, psum = 0.f, pq = 0.f, p2 = 0.f, gp = 1.f;
#pragma unroll
    for (int j = 0; j < 16; ++j) {
        p = fmaf(gf, p, rv[j]);
        gp *= gf;
        psum += p;
        pq = fmaf(gp, p, pq);
        p2 = fmaf(p, p, p2);
    }
    const double g = GAMMA;
    double gPT = g;
#pragma unroll
    for (int e = 0; e < 4; ++e) gPT *= gPT;     // g^16

    if (wid == 0) {
        // f64 wave path for the small-cnt region (cancellation-sensitive)
        double ig = gPT, iv = (double)p;
#pragma unroll
        for (int k = 1; k < 64; k <<= 1) {
            double og = __shfl_up(ig, k);
            double ov = __shfl_up(iv, k);
            if (lane >= k) { iv = fma(ig, ov, iv); ig *= og; }
        }
        double rho = __shfl_up(iv, 1), gexc = __shfl_up(ig, 1);
        if (lane == 0) { rho = 0.0; gexc = 1.0; }
        const double rin = fma(gexc, RinC, rho);
        const double G1 = g * (1.0 - gPT) / (1.0 - g);
        const double G2 = g * g * (1.0 - gPT * gPT) / (1.0 - g * g);
        double s1 = fma(rin, G1, (double)psum);
        double s2 = fma(rin * rin, G2, fma(2.0 * rin, (double)pq, (double)p2));
        double ia = s1, ib = s2;
#pragma unroll
        for (int k = 1; k < 64; k <<= 1) {
            double oa = __shfl_up(ia, k);
            double ob = __shfl_up(ib, k);
            if (lane >= k) { ia += oa; ib += ob; }
        }
        double ea = __shfl_up(ia, 1), eb = __shfl_up(ib, 1);
        if (lane == 0) { ea = 0.0; eb = 0.0; }
        double R = rin, S1 = S1C + ea, S2 = S2C + eb;
        const int a0 = lane * 17;
        const size_t gbase = (size_t)lane * 16;
        for (int j = 0; j < 16; ++j) {
            const float rf = rv[j];
            R = fma(g, R, (double)rf);
            S1 += R;
            S2 = fma(R, R, S2);
            float ov;
            if (gbase + j == 0) {
                ov = rf;                         // cnt < 2 -> std = 1
            } else {
                const double cnt = (double)(gbase + j + 1);
                const double inv = 1.0 / cnt;
                const double mean = S1 * inv;
                double var = fma(S2, inv, -(mean * mean));
                var = var > 0.0 ? var : 0.0;
                double sd = sqrt(var);
                sd = sd > 1e-8 ? sd : 1e-8;
                ov = (float)((double)rf / sd);
            }
            sbuf[w][a0 + j] = ov;
        }
    } else {
        // f32 wave path: cnt >= 1025, S2*cnt - S1^2 has no cancellation
        float ig = (float)gPT, iv = p;
#pragma unroll
        for (int k = 1; k < 64; k <<= 1) {
            float og = __shfl_up(ig, k);
            float ov = __shfl_up(iv, k);
            if (lane >= k) { iv = fmaf(ig, ov, iv); ig *= og; }
        }
        float rho = __shfl_up(iv, 1), gexc = __shfl_up(ig, 1);
        if (lane == 0) { rho = 0.f; gexc = 1.f; }
        const float rin = fmaf(gexc, (float)RinC, rho);
        const float G1f = (float)(g * (1.0 - gPT) / (1.0 - g));
        const float G2f = (float)(g * g * (1.0 - gPT * gPT) / (1.0 - g * g));
        float s1 = fmaf(rin, G1f, psum);
        float s2 = fmaf(rin * rin, G2f, fmaf(2.f * rin, pq, p2));
        float ia = s1, ib = s2;
#pragma unroll
        for (int k = 1; k < 64; k <<= 1) {
            float oa = __shfl_up(ia, k);
            float ob = __shfl_up(ib, k);
            if (lane >= k) { ia += oa; ib += ob; }
        }
        float ea = __shfl_up(ia, 1), eb = __shfl_up(ib, 1);
        if (lane == 0) { ea = 0.f; eb = 0.f; }
        const float S1bf = (float)S1C + ea;
        const float S2bf = (float)S2C + eb;

        float R = rin;
        float ls1 = 0.f, ls2 = 0.f;
        const float base_cnt = (float)((size_t)wid * 1024 + (size_t)lane * 16);
        const int a0 = lane * 17;
#pragma unroll
        for (int j = 0; j < 16; ++j) {
            const float rf = rv[j];
            R = fmaf(gf, R, rf);
            ls1 += R;
            ls2 = fmaf(R, R, ls2);
            const float cnt = base_cnt + (float)(j + 1);
            const float S1f = S1bf + ls1;
            const float S2f = S2bf + ls2;
            float t = fmaf(S2f, cnt, -(S1f * S1f));
            t = fmaxf(t, 1e-12f);
            sbuf[w][a0 + j] = rf * cnt * __builtin_amdgcn_rsqf(t);
        }
    }

    // wave-local sync only: this wave's ds_writes drain, then read own region.
    asm volatile("s_waitcnt lgkmcnt(0)" ::: "memory");

    float* dst = out + (size_t)wid * 1024;
#pragma unroll
    for (int k = 0; k < 4; ++k) {
        const int i = lane * 4 + k * 256;
        const int pp = padi16(i);
        vf4 v;
        v.x = sbuf[w][pp]; v.y = sbuf[w][pp + 1]; v.z = sbuf[w][pp + 2]; v.w = sbuf[w][pp + 3];
        __builtin_nontemporal_store(v, (vf4*)(dst + i));   // lane-contiguous full-line nt stores
    }
}

extern "C" void kernel_launch(void* const* d_in, const int* in_sizes, int n_in,
                              void* d_out, int out_size, void* d_ws, size_t ws_size,
                              hipStream_t stream) {
    (void)n_in; (void)out_size; (void)ws_size;
    const float* in = (const float*)d_in[0];
    float* out = (float*)d_out;
    double* ws = (double*)d_ws;
    const int n = in_sizes[0];

    const int nw = n >> 10;                     // 1024-elem wave chunks
    const int nc = nw >> 2;                     // 4096-elem block chunks
    // layout: bagg (4*nc f64) | bcar (3*nc f64) | wcar (3*nw f64) | aggf (nw float4)
    double* bagg = ws;
    double* bcar = bagg + 4 * (size_t)nc;
    double* wcar = bcar + 3 * (size_t)nc;
    vf4* aggf = (vf4*)(wcar + 3 * (size_t)nw);

    w_phase1<<<nc, THREADS, 0, stream>>>(in, aggf, bagg, nw);
    rs_phase2<4, 12><<<1, 1024, 0, stream>>>(bagg, bcar, nc);
    w_expand<<<(nc + THREADS - 1) / THREADS, THREADS, 0, stream>>>(bcar, aggf, wcar, nc);
    w_phase3<<<nc, THREADS, 0, stream>>>(in, out, wcar, nw);
}

// Round 14
// 51.145 us; speedup vs baseline: 1.4866x; 1.0501x over previous
//
#include <hip/hip_runtime.h>
#include <math.h>

#define THREADS 256
#define GAMMA 0.99

typedef float vf4 __attribute__((ext_vector_type(4)));   // native vector for nontemporal store

__device__ __forceinline__ int padi16(int i) { return i + (i >> 4); }   // lane stride 17 floats

// ---------- block-wide exclusive scan of linear transforms x -> g*x + v (f64) ----------
template<int NW>
__device__ __forceinline__ void block_compose_excl(int tid, double g, double v,
                                                   double& eg, double& ev,
                                                   double* lg, double* lv) {
    const int lane = tid & 63, wave = tid >> 6;
    double ig = g, iv = v;
#pragma unroll
    for (int k = 1; k < 64; k <<= 1) {
        double og = __shfl_up(ig, k);
        double ov = __shfl_up(iv, k);
        if (lane >= k) { iv = fma(ig, ov, iv); ig *= og; }
    }
    double weg = __shfl_up(ig, 1);
    double wev = __shfl_up(iv, 1);
    if (lane == 0) { weg = 1.0; wev = 0.0; }
    if (lane == 63) { lg[wave] = ig; lv[wave] = iv; }
    __syncthreads();
    double bg = 1.0, bv = 0.0;
    for (int w = 0; w < wave; ++w) { bv = fma(lg[w], bv, lv[w]); bg *= lg[w]; }
    eg = weg * bg;
    ev = fma(weg, bv, wev);
}

// ---------- block-wide exclusive additive scan of a pair (f64) ----------
template<int NW>
__device__ __forceinline__ void block_add_excl2(int tid, double a, double b,
                                                double& ea, double& eb,
                                                double* la, double* lb) {
    const int lane = tid & 63, wave = tid >> 6;
    double ia = a, ib = b;
#pragma unroll
    for (int k = 1; k < 64; k <<= 1) {
        double oa = __shfl_up(ia, k);
        double ob = __shfl_up(ib, k);
        if (lane >= k) { ia += oa; ib += ob; }
    }
    double wea = __shfl_up(ia, 1);
    double web = __shfl_up(ib, 1);
    if (lane == 0) { wea = 0.0; web = 0.0; }
    if (lane == 63) { la[wave] = ia; lb[wave] = ib; }
    __syncthreads();
    double ba = 0.0, bb = 0.0;
    for (int w = 0; w < wave; ++w) { ba += la[w]; bb += lb[w]; }
    ea = wea + ba;
    eb = web + bb;
}

// ================= wave-granular: chunk = 1024 elems per wave =================
// aggf[w] = float4{A,Ps,Pq,P2}   per 1024-elem wave chunk (f32-native)
// bagg[b*4+{A,Ps,Pq,P2}] (f64)   per 4096-elem block chunk
// bcar[b*3+{Rin,S1C,S2C}] (f64)  per block chunk (exclusive)

// ---------- P1: per-wave aggregates + block fold + chunk-0 exact epilogue ----------
__global__ __launch_bounds__(THREADS) void w_phase1(const float* __restrict__ in,
                                                    float* __restrict__ out,
                                                    vf4* __restrict__ aggf,
                                                    double* __restrict__ bagg, int nw) {
    __shared__ double sA[4], sPs[4], sPq[4], sP2[4];
    const int tid = threadIdx.x, lane = tid & 63, w = tid >> 6;
    const int wid = blockIdx.x * 4 + w;

    const float* src = in + (size_t)wid * 1024 + (size_t)lane * 16;
    float rv[16];
#pragma unroll
    for (int q = 0; q < 4; ++q) {
        const float4 t = ((const float4*)src)[q];
        rv[4 * q] = t.x; rv[4 * q + 1] = t.y; rv[4 * q + 2] = t.z; rv[4 * q + 3] = t.w;
    }
    const float gf = (float)GAMMA;
    float p = 0.f, psum = 0.f, pq = 0.f, p2 = 0.f, gp = 1.f;
#pragma unroll
    for (int j = 0; j < 16; ++j) {
        p = fmaf(gf, p, rv[j]);
        gp *= gf;
        psum += p;
        pq = fmaf(gp, p, pq);
        p2 = fmaf(p, p, p2);
    }
    const double g = GAMMA;
    double gPT = g;
#pragma unroll
    for (int e = 0; e < 4; ++e) gPT *= gPT;     // g^16

    float ig = (float)gPT, iv = p;
#pragma unroll
    for (int k = 1; k < 64; k <<= 1) {
        float og = __shfl_up(ig, k);
        float ov = __shfl_up(iv, k);
        if (lane >= k) { iv = fmaf(ig, ov, iv); ig *= og; }
    }
    float rho = __shfl_up(iv, 1), gexc = __shfl_up(ig, 1);
    if (lane == 0) { rho = 0.f; gexc = 1.f; }
    const float A = __shfl(iv, 63);             // wave-chunk end value (zero-init)

    const float G1f = (float)(g * (1.0 - gPT) / (1.0 - g));
    const float G2f = (float)(g * g * (1.0 - gPT * gPT) / (1.0 - g * g));
    float c1 = fmaf(rho, G1f, psum);
    float c2 = gexc * fmaf(rho, G2f, pq);
    float c3 = fmaf(rho * rho, G2f, fmaf(2.f * rho, pq, p2));
#pragma unroll
    for (int k = 32; k > 0; k >>= 1) {
        c1 += __shfl_down(c1, k);
        c2 += __shfl_down(c2, k);
        c3 += __shfl_down(c3, k);
    }
    if (lane == 0) {
        vf4 a; a.x = A; a.y = c1; a.z = c2; a.w = c3;
        aggf[wid] = a;
        sA[w] = (double)A; sPs[w] = (double)c1; sPq[w] = (double)c2; sP2[w] = (double)c3;
    }
    __syncthreads();
    if (tid == 0) {
        double gC = g;
#pragma unroll
        for (int e = 0; e < 10; ++e) gC *= gC;      // g^1024
        const double G1C = g * (1.0 - gC) / (1.0 - g);
        const double G2C = g * g * (1.0 - gC * gC) / (1.0 - g * g);
        double Rin = 0.0, Ps = 0.0, Pq = 0.0, P2 = 0.0, gex = 1.0;
#pragma unroll
        for (int i = 0; i < 4; ++i) {
            Ps += fma(Rin, G1C, sPs[i]);
            Pq += gex * fma(Rin, G2C, sPq[i]);
            P2 += fma(Rin * Rin, G2C, fma(2.0 * Rin, sPq[i], sP2[i]));
            Rin = fma(gC, Rin, sA[i]);
            gex *= gC;
        }
        bagg[4 * (size_t)blockIdx.x + 0] = Rin;
        bagg[4 * (size_t)blockIdx.x + 1] = Ps;
        bagg[4 * (size_t)blockIdx.x + 2] = Pq;
        bagg[4 * (size_t)blockIdx.x + 3] = P2;
    }

    // ---- chunk 0 (elems 0..1023): carries are identically zero -> exact f64 path ----
    if (blockIdx.x == 0 && w == 0) {
        double ig64 = gPT, iv64 = (double)p;
#pragma unroll
        for (int k = 1; k < 64; k <<= 1) {
            double og = __shfl_up(ig64, k);
            double ov = __shfl_up(iv64, k);
            if (lane >= k) { iv64 = fma(ig64, ov, iv64); ig64 *= og; }
        }
        double rin = __shfl_up(iv64, 1);
        if (lane == 0) rin = 0.0;
        const double G1 = g * (1.0 - gPT) / (1.0 - g);
        const double G2 = g * g * (1.0 - gPT * gPT) / (1.0 - g * g);
        double s1 = fma(rin, G1, (double)psum);
        double s2 = fma(rin * rin, G2, fma(2.0 * rin, (double)pq, (double)p2));
        double ia = s1, ib = s2;
#pragma unroll
        for (int k = 1; k < 64; k <<= 1) {
            double oa = __shfl_up(ia, k);
            double ob = __shfl_up(ib, k);
            if (lane >= k) { ia += oa; ib += ob; }
        }
        double ea = __shfl_up(ia, 1), eb = __shfl_up(ib, 1);
        if (lane == 0) { ea = 0.0; eb = 0.0; }
        double R = rin, S1 = ea, S2 = eb;
        const size_t gbase = (size_t)lane * 16;
        for (int j = 0; j < 16; ++j) {
            const float rf = rv[j];
            R = fma(g, R, (double)rf);
            S1 += R;
            S2 = fma(R, R, S2);
            float ov;
            if (gbase + j == 0) {
                ov = rf;                         // cnt < 2 -> std = 1
            } else {
                const double cnt = (double)(gbase + j + 1);
                const double inv = 1.0 / cnt;
                const double mean = S1 * inv;
                double var = fma(S2, inv, -(mean * mean));
                var = var > 0.0 ? var : 0.0;
                double sd = sqrt(var);
                sd = sd > 1e-8 ? sd : 1e-8;
                ov = (float)((double)rf / sd);
            }
            out[gbase + j] = ov;
        }
    }
}

// ---------- P2: scan block carries (verified) ----------
template<int CPT, int LOG2CHUNK>
__global__ __launch_bounds__(1024) void rs_phase2(const double* __restrict__ agg,
                                                  double* __restrict__ car, int nchunk) {
    __shared__ double lg[16], lv[16], la[16], lb[16];
    const int t = threadIdx.x;
    const double g = GAMMA;
    double gC = g;
#pragma unroll
    for (int e = 0; e < LOG2CHUNK; ++e) gC *= gC;   // g^CHUNKE

    double A[CPT], Ps[CPT], Pq[CPT], P2[CPT];
    const int c0 = t * CPT;
#pragma unroll
    for (int i = 0; i < CPT; ++i) {
        const int c = c0 + i;
        const bool ok = c < nchunk;
        A[i]  = ok ? agg[4 * (size_t)c + 0] : 0.0;
        Ps[i] = ok ? agg[4 * (size_t)c + 1] : 0.0;
        Pq[i] = ok ? agg[4 * (size_t)c + 2] : 0.0;
        P2[i] = ok ? agg[4 * (size_t)c + 3] : 0.0;
    }
    double mg = 1.0, mv = 0.0;
#pragma unroll
    for (int i = 0; i < CPT; ++i) { mv = fma(gC, mv, A[i]); mg *= gC; }

    double eg, ev;
    block_compose_excl<16>(t, mg, mv, eg, ev, lg, lv);

    const double G1C = g * (1.0 - gC) / (1.0 - g);
    const double G2C = g * g * (1.0 - gC * gC) / (1.0 - g * g);
    double Rin[CPT + 1];
    Rin[0] = ev;
    double s1[CPT], s2[CPT];
#pragma unroll
    for (int i = 0; i < CPT; ++i) {
        s1[i] = fma(Rin[i], G1C, Ps[i]);
        s2[i] = fma(Rin[i] * Rin[i], G2C, fma(2.0 * Rin[i], Pq[i], P2[i]));
        Rin[i + 1] = fma(gC, Rin[i], A[i]);
    }
    double ts1 = 0.0, ts2 = 0.0;
#pragma unroll
    for (int i = 0; i < CPT; ++i) { ts1 += s1[i]; ts2 += s2[i]; }
    double ea, eb;
    block_add_excl2<16>(t, ts1, ts2, ea, eb, la, lb);
#pragma unroll
    for (int i = 0; i < CPT; ++i) {
        const int c = c0 + i;
        if (c < nchunk) {
            car[3 * (size_t)c + 0] = Rin[i];
            car[3 * (size_t)c + 1] = ea;
            car[3 * (size_t)c + 2] = eb;
        }
        ea += s1[i];
        eb += s2[i];
    }
}

// ---------- P3: pure-f32 wave-independent rebase + emit; no barriers ----------
__global__ __launch_bounds__(THREADS) void w_phase3(const float* __restrict__ in,
                                                    float* __restrict__ out,
                                                    const double* __restrict__ bcar,
                                                    const vf4* __restrict__ aggf, int nw) {
    __shared__ float sbuf[THREADS / 64][1024 + 64];   // private per-wave region, stride 17/lane
    const int tid = threadIdx.x, lane = tid & 63, w = tid >> 6;
    const int wid = blockIdx.x * 4 + w;
    if (wid == 0) return;                             // chunk 0 written by P1 (no barriers here)
    const int b = blockIdx.x;

    const float* src = in + (size_t)wid * 1024 + (size_t)lane * 16;
    float rv[16];
#pragma unroll
    for (int q = 0; q < 4; ++q) {
        const float4 t = ((const float4*)src)[q];
        rv[4 * q] = t.x; rv[4 * q + 1] = t.y; rv[4 * q + 2] = t.z; rv[4 * q + 3] = t.w;
    }

    // block carry (f64 storage -> f32 math) + f32 expansion over preceding wave aggs
    const double g = GAMMA;
    double gW64 = g;
#pragma unroll
    for (int e = 0; e < 10; ++e) gW64 *= gW64;        // g^1024
    const float gW  = (float)gW64;
    const float G1W = (float)(g * (1.0 - gW64) / (1.0 - g));
    const float G2W = (float)(g * g * (1.0 - gW64 * gW64) / (1.0 - g * g));

    float Rc  = (float)bcar[3 * (size_t)b + 0];
    float S1C = (float)bcar[3 * (size_t)b + 1];
    float S2C = (float)bcar[3 * (size_t)b + 2];
    for (int i = 0; i < w; ++i) {                     // w <= 3, wave-uniform
        const vf4 a = aggf[4 * (size_t)b + i];
        S1C += fmaf(Rc, G1W, a.y);
        S2C += fmaf(Rc * Rc, G2W, fmaf(2.f * Rc, a.z, a.w));
        Rc = fmaf(gW, Rc, a.x);
    }

    const float gf = (float)GAMMA;
    float p = 0.f, psum = 0.f, pq = 0.f, p2 = 0.f, gp = 1.f;
#pragma unroll
    for (int j = 0; j < 16; ++j) {
        p = fmaf(gf, p, rv[j]);
        gp *= gf;
        psum += p;
        pq = fmaf(gp, p, pq);
        p2 = fmaf(p, p, p2);
    }
    double gPT64 = g;
#pragma unroll
    for (int e = 0; e < 4; ++e) gPT64 *= gPT64;       // g^16

    float ig = (float)gPT64, iv = p;
#pragma unroll
    for (int k = 1; k < 64; k <<= 1) {
        float og = __shfl_up(ig, k);
        float ov = __shfl_up(iv, k);
        if (lane >= k) { iv = fmaf(ig, ov, iv); ig *= og; }
    }
    float rho = __shfl_up(iv, 1), gexc = __shfl_up(ig, 1);
    if (lane == 0) { rho = 0.f; gexc = 1.f; }
    const float rin = fmaf(gexc, Rc, rho);
    const float G1f = (float)(g * (1.0 - gPT64) / (1.0 - g));
    const float G2f = (float)(g * g * (1.0 - gPT64 * gPT64) / (1.0 - g * g));
    float s1 = fmaf(rin, G1f, psum);
    float s2 = fmaf(rin * rin, G2f, fmaf(2.f * rin, pq, p2));
    float ia = s1, ib = s2;
#pragma unroll
    for (int k = 1; k < 64; k <<= 1) {
        float oa = __shfl_up(ia, k);
        float ob = __shfl_up(ib, k);
        if (lane >= k) { ia += oa; ib += ob; }
    }
    float ea = __shfl_up(ia, 1), eb = __shfl_up(ib, 1);
    if (lane == 0) { ea = 0.f; eb = 0.f; }
    const float S1bf = S1C + ea;
    const float S2bf = S2C + eb;

    // out = rf * cnt * rsqrt(S2*cnt - S1^2)   (no cancellation at cnt >= 1025)
    float R = rin;
    float ls1 = 0.f, ls2 = 0.f;
    const float base_cnt = (float)((size_t)wid * 1024 + (size_t)lane * 16);
    const int a0 = lane * 17;
#pragma unroll
    for (int j = 0; j < 16; ++j) {
        const float rf = rv[j];
        R = fmaf(gf, R, rf);
        ls1 += R;
        ls2 = fmaf(R, R, ls2);
        const float cnt = base_cnt + (float)(j + 1);
        const float S1f = S1bf + ls1;
        const float S2f = S2bf + ls2;
        float t = fmaf(S2f, cnt, -(S1f * S1f));
        t = fmaxf(t, 1e-12f);
        sbuf[w][a0 + j] = rf * cnt * __builtin_amdgcn_rsqf(t);
    }

    // wave-local sync only: this wave's ds_writes drain, then read own region.
    asm volatile("s_waitcnt lgkmcnt(0)" ::: "memory");

    float* dst = out + (size_t)wid * 1024;
#pragma unroll
    for (int k = 0; k < 4; ++k) {
        const int i = lane * 4 + k * 256;
        const int pp = padi16(i);
        vf4 v;
        v.x = sbuf[w][pp]; v.y = sbuf[w][pp + 1]; v.z = sbuf[w][pp + 2]; v.w = sbuf[w][pp + 3];
        __builtin_nontemporal_store(v, (vf4*)(dst + i));   // lane-contiguous full-line nt stores
    }
}

extern "C" void kernel_launch(void* const* d_in, const int* in_sizes, int n_in,
                              void* d_out, int out_size, void* d_ws, size_t ws_size,
                              hipStream_t stream) {
    (void)n_in; (void)out_size; (void)ws_size;
    const float* in = (const float*)d_in[0];
    float* out = (float*)d_out;
    double* ws = (double*)d_ws;
    const int n = in_sizes[0];

    const int nw = n >> 10;                     // 1024-elem wave chunks
    const int nc = nw >> 2;                     // 4096-elem block chunks
    // layout: bagg (4*nc f64) | bcar (3*nc f64) | aggf (nw float4)
    double* bagg = ws;
    double* bcar = bagg + 4 * (size_t)nc;
    vf4* aggf = (vf4*)(bcar + 3 * (size_t)nc);

    w_phase1<<<nc, THREADS, 0, stream>>>(in, out, aggf, bagg, nw);
    rs_phase2<4, 12><<<1, 1024, 0, stream>>>(bagg, bcar, nc);
    w_phase3<<<nc, THREADS, 0, stream>>>(in, out, bcar, aggf, nw);
}